// Round 4
// baseline (246.518 us; speedup 1.0000x reference)
//
#include <hip/hip_runtime.h>
#include <math.h>

#define T_TOK 2048
#define DM 1024
#define HQ 16
#define HD 64
#define NB 32
#define BS 64
#define S_SEL 16
#define NEGF (-1e30f)

typedef __attribute__((ext_vector_type(8))) short bf16x8;
typedef __attribute__((ext_vector_type(4))) float f32x4;
typedef unsigned short ush;

__device__ __forceinline__ ush f2bf(float x) {
  unsigned u = __float_as_uint(x);
  return (ush)((u + 0x7fffu + ((u >> 16) & 1u)) >> 16);
}
__device__ __forceinline__ float bf2f(ush h) {
  return __uint_as_float(((unsigned)h) << 16);
}

// ---- decompose weights + x into bf16 hi/lo planes; seg 6 zeroes d_out -------
__global__ __launch_bounds__(256) void split_w7(
    const float* __restrict__ s0, const float* __restrict__ s1,
    const float* __restrict__ s2, const float* __restrict__ s3,
    const float* __restrict__ s4, const float* __restrict__ s5,
    ush* h0, ush* l0, ush* h1, ush* l1, ush* h2, ush* l2,
    ush* h3, ush* l3, ush* h4, ush* l4, ush* h5, ush* l5,
    float* __restrict__ zout)
{
  int seg = blockIdx.y;
  if (seg == 6) {
    int i = blockIdx.x * 256 + threadIdx.x;
    if (i < (T_TOK*DM)/4) ((float4*)zout)[i] = make_float4(0.f,0.f,0.f,0.f);
    return;
  }
  const float* srcs[6] = {s0, s1, s2, s3, s4, s5};
  ush* hs[6] = {h0, h1, h2, h3, h4, h5};
  ush* ls[6] = {l0, l1, l2, l3, l4, l5};
  const int ns[6] = {1048576, 65536, 65536, 49152, 1048576, 2097152};
  int i = (blockIdx.x * 256 + threadIdx.x) * 4;
  if (i >= ns[seg]) return;
  float4 v = *(const float4*)(srcs[seg] + i);
  ushort4 hv, lv;
  hv.x = f2bf(v.x); lv.x = f2bf(v.x - bf2f(hv.x));
  hv.y = f2bf(v.y); lv.y = f2bf(v.y - bf2f(hv.y));
  hv.z = f2bf(v.z); lv.z = f2bf(v.z - bf2f(hv.z));
  hv.w = f2bf(v.w); lv.w = f2bf(v.w - bf2f(hv.w));
  *(ushort4*)(hs[seg] + i) = hv;
  *(ushort4*)(ls[seg] + i) = lv;
}

// ---- split-bf16 MFMA GEMM body: Y = A @ W^T, 64x64 tile ---------------------
__device__ __forceinline__ void gemm64_body(
    const float* __restrict__ Af,
    const ush* __restrict__ Ah_, const ush* __restrict__ Al_,
    const ush* __restrict__ Wh, const ush* __restrict__ Wl,
    float* Yf, ush* Yh, ush* Yl, ush* YT, int useAtomic,
    ush* Ch, ush* Cl, int ctrans, int cidx, float (*cent)[64],
    int N, int K, int kStart, int kEnd, int m0, int n0,
    ush Ash[64][40], ush Asl[64][40], ush Bsh[64][40], ush Bsl[64][40])
{
  const int tid = threadIdx.x;
  const int wave = tid >> 6, lane = tid & 63;
  const int quad = lane >> 4, c16 = lane & 15;
  const int wm = wave >> 1, wn = wave & 1;
  const int ar = tid >> 2, ac = (tid & 3) * 8;
  f32x4 acc[2][2] = {};
  for (int k0 = kStart; k0 < kEnd; k0 += 32) {
    __syncthreads();
    if (Af) {
      const float* src = Af + (size_t)(m0 + ar) * K + k0 + ac;
      float4 u = *(const float4*)(src);
      float4 w2 = *(const float4*)(src + 4);
      float f[8] = {u.x, u.y, u.z, u.w, w2.x, w2.y, w2.z, w2.w};
      bf16x8 hv, lv;
      #pragma unroll
      for (int j = 0; j < 8; ++j) {
        ush hb = f2bf(f[j]);
        hv[j] = (short)hb;
        lv[j] = (short)f2bf(f[j] - bf2f(hb));
      }
      *(bf16x8*)&Ash[ar][ac] = hv;
      *(bf16x8*)&Asl[ar][ac] = lv;
    } else {
      *(bf16x8*)&Ash[ar][ac] = *(const bf16x8*)(Ah_ + (size_t)(m0 + ar) * K + k0 + ac);
      *(bf16x8*)&Asl[ar][ac] = *(const bf16x8*)(Al_ + (size_t)(m0 + ar) * K + k0 + ac);
    }
    {
      bf16x8 bh = {}, bl = {};
      if (n0 + ar < N) {
        bh = *(const bf16x8*)(Wh + (size_t)(n0 + ar) * K + k0 + ac);
        bl = *(const bf16x8*)(Wl + (size_t)(n0 + ar) * K + k0 + ac);
      }
      *(bf16x8*)&Bsh[ar][ac] = bh;
      *(bf16x8*)&Bsl[ar][ac] = bl;
    }
    __syncthreads();
    bf16x8 Ah[2], Al[2], Bh[2], Bl[2];
    #pragma unroll
    for (int mt = 0; mt < 2; ++mt) {
      Ah[mt] = *(const bf16x8*)&Ash[wm*32 + mt*16 + c16][quad*8];
      Al[mt] = *(const bf16x8*)&Asl[wm*32 + mt*16 + c16][quad*8];
    }
    #pragma unroll
    for (int nt = 0; nt < 2; ++nt) {
      Bh[nt] = *(const bf16x8*)&Bsh[wn*32 + nt*16 + c16][quad*8];
      Bl[nt] = *(const bf16x8*)&Bsl[wn*32 + nt*16 + c16][quad*8];
    }
    #pragma unroll
    for (int mt = 0; mt < 2; ++mt)
      #pragma unroll
      for (int nt = 0; nt < 2; ++nt) {
        acc[mt][nt] = __builtin_amdgcn_mfma_f32_16x16x32_bf16(Ah[mt], Bh[nt], acc[mt][nt], 0, 0, 0);
        acc[mt][nt] = __builtin_amdgcn_mfma_f32_16x16x32_bf16(Ah[mt], Bl[nt], acc[mt][nt], 0, 0, 0);
        acc[mt][nt] = __builtin_amdgcn_mfma_f32_16x16x32_bf16(Al[mt], Bh[nt], acc[mt][nt], 0, 0, 0);
      }
  }
  #pragma unroll
  for (int mt = 0; mt < 2; ++mt)
    #pragma unroll
    for (int nt = 0; nt < 2; ++nt) {
      int n = n0 + wn*32 + nt*16 + c16;
      if (n < N) {
        #pragma unroll
        for (int r = 0; r < 4; ++r) {
          int m = m0 + wm*32 + mt*16 + quad*4 + r;
          float vvv = acc[mt][nt][r];
          if (Yf) {
            if (useAtomic) atomicAdd(&Yf[(size_t)m*N + n], vvv);
            else Yf[(size_t)m*N + n] = vvv;
          }
          ush hb = f2bf(vvv);
          if (Yh) {
            Yh[(size_t)m*N + n] = hb;
            if (Yl) Yl[(size_t)m*N + n] = f2bf(vvv - bf2f(hb));
          }
          if (YT) YT[(size_t)n*T_TOK + m] = hb;
        }
      }
    }
  if (Ch) {
    float ps[2];
    #pragma unroll
    for (int nt = 0; nt < 2; ++nt) {
      ps[nt] = 0.f;
      #pragma unroll
      for (int mt = 0; mt < 2; ++mt)
        #pragma unroll
        for (int r = 0; r < 4; ++r) ps[nt] += acc[mt][nt][r];
      ps[nt] += __shfl_xor(ps[nt], 16);
      ps[nt] += __shfl_xor(ps[nt], 32);
      if (quad == 0) cent[wm][wn*32 + nt*16 + c16] = ps[nt];
    }
    __syncthreads();
    if (wm == 0 && quad == 0) {
      #pragma unroll
      for (int nt = 0; nt < 2; ++nt) {
        int n = wn*32 + nt*16 + c16;
        float mval = (cent[0][n] + cent[1][n]) * (1.f/64.f);
        ush hb = f2bf(mval);
        ush lb = f2bf(mval - bf2f(hb));
        if (!ctrans) { Ch[cidx*HD + n] = hb; Cl[cidx*HD + n] = lb; }
        else         { Ch[n*NB + cidx] = hb; Cl[n*NB + cidx] = lb; }
      }
    }
  }
}

// fused q + k/v/g projections (+ centroid pooling) in one dispatch
__global__ __launch_bounds__(256) void gemm_proj(
    const ush* __restrict__ xh, const ush* __restrict__ xl,
    const ush* __restrict__ Wqh, const ush* __restrict__ Wql,
    const ush* __restrict__ Wkh, const ush* __restrict__ Wkl,
    const ush* __restrict__ Wvh, const ush* __restrict__ Wvl,
    const ush* __restrict__ Wgh, const ush* __restrict__ Wgl,
    ush* qbh, ush* qbl, ush* kb, ush* vbT, float* gpj,
    ush* kch, ush* kcl, ush* vth, ush* vtl, int K)
{
  __shared__ ush Ash[64][40], Asl[64][40], Bsh[64][40], Bsl[64][40];
  __shared__ float cent[2][64];
  const int bx = blockIdx.x;
  if (bx < 16) {
    gemm64_body(nullptr, xh, xl, Wqh, Wql, nullptr, qbh, qbl, nullptr, 0,
                nullptr, nullptr, 0, 0, nullptr,
                DM, K, 0, K, blockIdx.y*64, bx*64, Ash, Asl, Bsh, Bsl);
  } else if (bx == 16) {
    gemm64_body(nullptr, xh, xl, Wkh, Wkl, nullptr, kb, nullptr, nullptr, 0,
                kch, kcl, 0, blockIdx.y, cent,
                HD, K, 0, K, blockIdx.y*64, 0, Ash, Asl, Bsh, Bsl);
  } else if (bx == 17) {
    gemm64_body(nullptr, xh, xl, Wvh, Wvl, nullptr, nullptr, nullptr, vbT, 0,
                vth, vtl, 1, blockIdx.y, cent,
                HD, K, 0, K, blockIdx.y*64, 0, Ash, Asl, Bsh, Bsl);
  } else {
    gemm64_body(nullptr, xh, xl, Wgh, Wgl, gpj, nullptr, nullptr, nullptr, 0,
                nullptr, nullptr, 0, 0, nullptr,
                48, K, 0, K, blockIdx.y*64, 0, Ash, Asl, Bsh, Bsl);
  }
}

// out-projection: A = f32 o inline split; SPLIT-K=2 via f32 atomics
__global__ __launch_bounds__(256) void gemm_out_sk(
    const float* __restrict__ Af,
    const ush* __restrict__ Wh, const ush* __restrict__ Wl,
    float* Yf, int N, int K)
{
  __shared__ ush Ash[64][40], Asl[64][40], Bsh[64][40], Bsl[64][40];
  const int kHalf = K >> 1;
  const int kStart = blockIdx.z * kHalf;
  gemm64_body(Af, nullptr, nullptr, Wh, Wl, Yf, nullptr, nullptr, nullptr, 1,
              nullptr, nullptr, 0, 0, nullptr,
              N, K, kStart, kStart + kHalf, blockIdx.y*64, blockIdx.x*64,
              Ash, Asl, Bsh, Bsl);
}

// ---- compressed attention + top-k, MFMA, one wave per token (4 tokens/WG) ---
__global__ __launch_bounds__(256) void cmp_attn_mfma(
    const ush* __restrict__ qh, const ush* __restrict__ ql,
    const ush* __restrict__ kch, const ush* __restrict__ kcl,
    const ush* __restrict__ vth, const ush* __restrict__ vtl,
    float* __restrict__ ocmp, int* __restrict__ blkp)
{
  __shared__ float Pls[4][16][36];
  const int tid = threadIdx.x, w = tid >> 6, lane = tid & 63;
  const int quad = lane >> 4, c16 = lane & 15;
  const int t = blockIdx.x * 4 + w;

  const ush* qrh = qh + (size_t)t*DM + c16*HD + quad*8;
  const ush* qrl = ql + (size_t)t*DM + c16*HD + quad*8;
  bf16x8 qah0 = *(const bf16x8*)(qrh);
  bf16x8 qah1 = *(const bf16x8*)(qrh + 32);
  bf16x8 qal0 = *(const bf16x8*)(qrl);
  bf16x8 qal1 = *(const bf16x8*)(qrl + 32);

  f32x4 s[2];
  #pragma unroll
  for (int nh = 0; nh < 2; ++nh) {
    const int crow = nh*16 + c16;
    bf16x8 kh0 = *(const bf16x8*)(kch + crow*HD + quad*8);
    bf16x8 kh1 = *(const bf16x8*)(kch + crow*HD + 32 + quad*8);
    bf16x8 kl0 = *(const bf16x8*)(kcl + crow*HD + quad*8);
    bf16x8 kl1 = *(const bf16x8*)(kcl + crow*HD + 32 + quad*8);
    f32x4 acc = {0.f, 0.f, 0.f, 0.f};
    acc = __builtin_amdgcn_mfma_f32_16x16x32_bf16(qah0, kh0, acc, 0, 0, 0);
    acc = __builtin_amdgcn_mfma_f32_16x16x32_bf16(qah1, kh1, acc, 0, 0, 0);
    acc = __builtin_amdgcn_mfma_f32_16x16x32_bf16(qah0, kl0, acc, 0, 0, 0);
    acc = __builtin_amdgcn_mfma_f32_16x16x32_bf16(qah1, kl1, acc, 0, 0, 0);
    acc = __builtin_amdgcn_mfma_f32_16x16x32_bf16(qal0, kh0, acc, 0, 0, 0);
    acc = __builtin_amdgcn_mfma_f32_16x16x32_bf16(qal1, kh1, acc, 0, 0, 0);
    s[nh] = acc;
  }

  const int nvis = (t + 1) >> 6;
  const bool visA = (c16 < nvis), visB = (16 + c16 < nvis);
  float p[2][4];
  float iA = 0.f, iB = 0.f;
  #pragma unroll
  for (int r = 0; r < 4; ++r) {
    float sA = s[0][r] * 0.125f, sB = s[1][r] * 0.125f;
    float m = fmaxf(visA ? sA : -INFINITY, visB ? sB : -INFINITY);
    #pragma unroll
    for (int off = 1; off < 16; off <<= 1) m = fmaxf(m, __shfl_xor(m, off));
    float eA = visA ? __expf(sA - m) : 0.f;
    float eB = visB ? __expf(sB - m) : 0.f;
    float l = eA + eB;
    #pragma unroll
    for (int off = 1; off < 16; off <<= 1) l += __shfl_xor(l, off);
    float inv = (l > 0.f) ? 1.f / l : 0.f;
    p[0][r] = eA * inv; p[1][r] = eB * inv;
    iA += p[0][r]; iB += p[1][r];
  }
  iA += __shfl_xor(iA, 16); iA += __shfl_xor(iA, 32);
  iB += __shfl_xor(iB, 16); iB += __shfl_xor(iB, 32);

  #pragma unroll
  for (int nh = 0; nh < 2; ++nh)
    #pragma unroll
    for (int r = 0; r < 4; ++r)
      Pls[w][quad*4 + r][nh*16 + c16] = p[nh][r];

  {
    const int cur = t >> 6;
    float a;
    if (lane < 16) a = iA;
    else if (lane < 32) a = iB;
    else a = -INFINITY;
    if (lane < 32) {
      if (lane > cur) a = NEGF;
      if (lane == 0 || lane == cur) a = INFINITY;
    }
    for (int sidx = 0; sidx < S_SEL; ++sidx) {
      float bv = a; int bi = lane;
      #pragma unroll
      for (int off = 1; off < 64; off <<= 1) {
        float ov = __shfl_xor(bv, off); int oi = __shfl_xor(bi, off);
        if (ov > bv || (ov == bv && oi < bi)) { bv = ov; bi = oi; }
      }
      if (lane == 0) blkp[t*S_SEL + sidx] = bi;
      if (lane == bi) a = -INFINITY;
    }
  }
  __syncthreads();

  float4 pa = *(const float4*)&Pls[w][c16][quad*8];
  float4 pb = *(const float4*)&Pls[w][c16][quad*8 + 4];
  float pf[8] = {pa.x, pa.y, pa.z, pa.w, pb.x, pb.y, pb.z, pb.w};
  bf16x8 pah, pal;
  #pragma unroll
  for (int j = 0; j < 8; ++j) {
    ush hb = f2bf(pf[j]);
    pah[j] = (short)hb;
    pal[j] = (short)f2bf(pf[j] - bf2f(hb));
  }
  #pragma unroll
  for (int nb = 0; nb < 4; ++nb) {
    const int drow = nb*16 + c16;
    bf16x8 vh8 = *(const bf16x8*)(vth + drow*NB + quad*8);
    bf16x8 vl8 = *(const bf16x8*)(vtl + drow*NB + quad*8);
    f32x4 acc = {0.f, 0.f, 0.f, 0.f};
    acc = __builtin_amdgcn_mfma_f32_16x16x32_bf16(pah, vh8, acc, 0, 0, 0);
    acc = __builtin_amdgcn_mfma_f32_16x16x32_bf16(pah, vl8, acc, 0, 0, 0);
    acc = __builtin_amdgcn_mfma_f32_16x16x32_bf16(pal, vh8, acc, 0, 0, 0);
    #pragma unroll
    for (int r = 0; r < 4; ++r)
      ocmp[(size_t)t*DM + (quad*4 + r)*HD + nb*16 + c16] = acc[r];
  }
}

// ---- selected attention: 16 waves per token, ONE block per wave -------------
// Rounds 0-2 proved this dispatch is latency-bound with a conserved per-wave
// serial cost (56/56/78us across three loop-body variants; VALU<22%, MFMA<5%,
// HBM<4%). Fix is structural: the 4-deep per-wave block loop becomes 16 waves
// x 1 block (WG=1024). Per-wave critical path = ONE {K->QK->exp->PV} chain
// (swapped-operand form, zero loop LDS — validated in R2), then an 8-slot
// binary tree combine in LDS. Epilogue operands (o_cmp, gates) prefetch at
// kernel entry; final RMW is fully coalesced over all 1024 threads.
// R3 bench was an infra failure (container died twice, no dispatch profile);
// kernel audited for launchability (VGPR<=128 via launch_bounds, LDS 41.5KB),
// OOB (max blk=31 -> all reads in-bounds) and barrier divergence (none) —
// resubmitted unchanged.
__global__ __launch_bounds__(1024, 1) void sel_attn_16w(
    const ush* __restrict__ qbh, const ush* __restrict__ kb,
    const ush* __restrict__ vbT, const float* __restrict__ gp,
    const int* __restrict__ blkp, float* __restrict__ ocmp_io)
{
  __shared__ float bufO[8][64][20];   // 40 KB; pad 20 -> writes max 2-way
  __shared__ float bufL[8][16];

  const int tid = threadIdx.x, w = tid >> 6, lane = tid & 63;
  const int quad = lane >> 4, c16 = lane & 15;
  const int t = T_TOK - 1 - blockIdx.x;         // heavy tokens first
  const int cur = t >> 6;
  const int nblk = (cur + 1 < S_SEL) ? cur + 1 : S_SEL;

  // epilogue operands: issue first, consumed last
  const size_t oidx = (size_t)t*DM + (size_t)w*HD + lane;
  const float oc = ocmp_io[oidx];
  const float ga = gp[(size_t)t*48 + w*3 + 0];
  const float gb = gp[(size_t)t*48 + w*3 + 1];

  f32x4 accO[4] = {};                 // O^T[d = dn*16+quad*4+r][h = c16]
  float lacc = 0.f;                   // denom partial for head c16

  if (w < nblk) {
    const int bs = blkp[t*S_SEL + w] * BS;      // uniform per wave -> s_load

    // Q fragment (head = c16, d = quad*8+j / +32)
    const ush* qrow = qbh + (size_t)t*DM + c16*HD + quad*8;
    bf16x8 qa0 = *(const bf16x8*)(qrow);
    bf16x8 qa1 = *(const bf16x8*)(qrow + 32);

    // K fragments: A-operand rows = keys (nc*16 + c16), k = d
    bf16x8 kf0[4], kf1[4];
    #pragma unroll
    for (int nc = 0; nc < 4; ++nc) {
      const ush* kp = kb + (size_t)(bs + nc*16 + c16) * HD + quad*8;
      kf0[nc] = *(const bf16x8*)(kp);
      kf1[nc] = *(const bf16x8*)(kp + 32);
    }

    // V fragments issued early so latency hides under QK + exp/pack
    bf16x8 vf[4][2];
    #pragma unroll
    for (int dn = 0; dn < 4; ++dn) {
      const ush* vrow = vbT + (size_t)(dn*16 + c16) * T_TOK + bs + quad*4;
      #pragma unroll
      for (int p = 0; p < 2; ++p) {
        uint2 lo = *(const uint2*)(vrow + p*32);        // keys p*32 + q*4+j
        uint2 hi = *(const uint2*)(vrow + p*32 + 16);   // keys p*32+16+q*4+j
        int4 tmp = make_int4((int)lo.x, (int)lo.y, (int)hi.x, (int)hi.y);
        vf[dn][p] = *(bf16x8*)&tmp;
      }
    }

    // S^T = K Q^T  (lane: head = c16, key = bs + nc*16 + quad*4 + r)
    f32x4 sc[4];
    #pragma unroll
    for (int nc = 0; nc < 4; ++nc) {
      f32x4 a = {0.f, 0.f, 0.f, 0.f};
      a = __builtin_amdgcn_mfma_f32_16x16x32_bf16(kf0[nc], qa0, a, 0, 0, 0);
      a = __builtin_amdgcn_mfma_f32_16x16x32_bf16(kf1[nc], qa1, a, 0, 0, 0);
      sc[nc] = a;
    }

    // mask + exp + pack: P^T stays in registers as two B-fragments
    ush pf[16];
    #pragma unroll
    for (int nc = 0; nc < 4; ++nc) {
      const int k0 = bs + nc*16 + quad*4;
      #pragma unroll
      for (int r = 0; r < 4; ++r) {
        float e = (k0 + r <= t) ? __expf(sc[nc][r] * 0.125f) : 0.f;
        lacc += e;
        pf[nc*4 + r] = f2bf(e);
      }
    }
    bf16x8 P01, P23;
    #pragma unroll
    for (int j = 0; j < 8; ++j) {
      P01[j] = (short)pf[j];
      P23[j] = (short)pf[8 + j];
    }

    // O^T += V^T P^T (two 16-key chunks per MFMA)
    #pragma unroll
    for (int dn = 0; dn < 4; ++dn) {
      accO[dn] = __builtin_amdgcn_mfma_f32_16x16x32_bf16(vf[dn][0], P01, accO[dn], 0, 0, 0);
      accO[dn] = __builtin_amdgcn_mfma_f32_16x16x32_bf16(vf[dn][1], P23, accO[dn], 0, 0, 0);
    }
  }

  // denom: sum over quads -> every lane holds full per-head sum
  lacc += __shfl_xor(lacc, 16);
  lacc += __shfl_xor(lacc, 32);

  // ---- binary-tree cross-wave combine (stages 8,4,2,1) ----
#define TREE_STAGE(S)                                                   \
  if (w >= (S) && w < 2*(S)) {                                          \
    _Pragma("unroll")                                                   \
    for (int dn = 0; dn < 4; ++dn)                                      \
      _Pragma("unroll")                                                 \
      for (int r = 0; r < 4; ++r)                                       \
        bufO[w-(S)][dn*16 + quad*4 + r][c16] = accO[dn][r];             \
    if (quad == 0) bufL[w-(S)][c16] = lacc;                             \
  }                                                                     \
  __syncthreads();                                                      \
  if (w < (S)) {                                                        \
    _Pragma("unroll")                                                   \
    for (int dn = 0; dn < 4; ++dn)                                      \
      _Pragma("unroll")                                                 \
      for (int r = 0; r < 4; ++r)                                       \
        accO[dn][r] += bufO[w][dn*16 + quad*4 + r][c16];                \
    lacc += bufL[w][c16];                                               \
  }                                                                     \
  __syncthreads();

  TREE_STAGE(8)
  TREE_STAGE(4)
  TREE_STAGE(2)
  TREE_STAGE(1)
#undef TREE_STAGE

  // wave 0 publishes the total; all 16 waves emit coalesced output
  if (w == 0) {
    #pragma unroll
    for (int dn = 0; dn < 4; ++dn)
      #pragma unroll
      for (int r = 0; r < 4; ++r)
        bufO[0][dn*16 + quad*4 + r][c16] = accO[dn][r];
    if (quad == 0) bufL[0][c16] = lacc;
  }
  __syncthreads();

  {
    const float L = bufL[0][w];                 // head h = w (wave-uniform)
    const float O = bufO[0][lane][w];           // d = lane
    const float gcv = 1.f/(1.f + __expf(-ga));
    const float gsv = 1.f/(1.f + __expf(-gb));
    ocmp_io[oidx] = O * gsv / L + oc * gcv;
  }
}

extern "C" void kernel_launch(void* const* d_in, const int* in_sizes, int n_in,
                              void* d_out, int out_size, void* d_ws, size_t ws_size,
                              hipStream_t stream)
{
  const float* x  = (const float*)d_in[0];
  const float* Wq = (const float*)d_in[1];
  const float* Wk = (const float*)d_in[2];
  const float* Wv = (const float*)d_in[3];
  const float* Wg = (const float*)d_in[4];
  const float* Wo = (const float*)d_in[5];
  float* out = (float*)d_out;

  float* ws   = (float*)d_ws;
  float* gpj  = ws;                                // 2048*48 f32
  float* ocmp = gpj + (size_t)T_TOK*48;            // 2048*1024 f32 (combined o)
  ush* xh  = (ush*)(ocmp + (size_t)T_TOK*DM);      // 2048*1024
  ush* xl  = xh + (size_t)T_TOK*DM;
  ush* qbh = xl + (size_t)T_TOK*DM;
  ush* qbl = qbh + (size_t)T_TOK*DM;
  ush* kb  = qbl + (size_t)T_TOK*DM;               // 2048*64
  ush* vbT = kb  + (size_t)T_TOK*HD;               // 64*2048 (transposed)
  ush* kch = vbT + (size_t)T_TOK*HD;
  ush* kcl = kch + NB*HD;
  ush* vth = kcl + NB*HD;
  ush* vtl = vth + NB*HD;
  ush* Wqh = vtl + NB*HD;
  ush* Wql = Wqh + 1048576;
  ush* Wkh = Wql + 1048576;
  ush* Wkl = Wkh + 65536;
  ush* Wvh = Wkl + 65536;
  ush* Wvl = Wvh + 65536;
  ush* Wgh = Wvl + 65536;
  ush* Wgl = Wgh + 49152;
  ush* Woh = Wgl + 49152;
  ush* Wol = Woh + 1048576;
  int* blkp = (int*)(Wol + 1048576);               // 2048*16

  split_w7<<<dim3(2048, 7), 256, 0, stream>>>(Wq, Wk, Wv, Wg, Wo, x,
      Wqh, Wql, Wkh, Wkl, Wvh, Wvl, Wgh, Wgl, Woh, Wol, xh, xl, out);
  gemm_proj<<<dim3(19, 32), 256, 0, stream>>>(xh, xl, Wqh, Wql,
      Wkh, Wkl, Wvh, Wvl, Wgh, Wgl, qbh, qbl, kb, vbT, gpj,
      kch, kcl, vth, vtl, DM);
  cmp_attn_mfma<<<T_TOK/4, 256, 0, stream>>>(qbh, qbl, kch, kcl, vth, vtl,
      ocmp, blkp);
  sel_attn_16w<<<T_TOK, 1024, 0, stream>>>(qbh, kb, vbT, gpj, blkp, ocmp);
  gemm_out_sk<<<dim3(16, 32, 2), 256, 0, stream>>>(ocmp, Woh, Wol, out, DM, DM);
}

// Round 5
// 179.759 us; speedup vs baseline: 1.3714x; 1.3714x over previous
//
#include <hip/hip_runtime.h>
#include <math.h>

#define T_TOK 2048
#define DM 1024
#define HQ 16
#define HD 64
#define NB 32
#define BS 64
#define S_SEL 16
#define NEGF (-1e30f)

typedef __attribute__((ext_vector_type(8))) short bf16x8;
typedef __attribute__((ext_vector_type(4))) float f32x4;
typedef unsigned short ush;

__device__ __forceinline__ ush f2bf(float x) {
  unsigned u = __float_as_uint(x);
  return (ush)((u + 0x7fffu + ((u >> 16) & 1u)) >> 16);
}
__device__ __forceinline__ float bf2f(ush h) {
  return __uint_as_float(((unsigned)h) << 16);
}

// ============================================================================
// FRAGMENT-ORDER LAYOUTS (R4 theory: all attn loads were 64-way gathers, ~64
// L1 transactions each; time across R0-R4 tracked gather count, not occupancy/
// VALU/LDS. Fix: store K/V/Q in MFMA-fragment order so every attn load is
// base + lane*16B, fully coalesced.)
//   qbF[t]:  idx = t*1024 + half*512 + quad*128 + head*8 + j    (d=half*32+quad*8+j)
//   kbF[b]:  idx = b*4096 + nc*1024 + half*512 + quad*128 + ck*8 + j
//            (key=b*64+nc*16+ck, d=half*32+quad*8+j)
//   vbF[b]:  idx = b*4096 + (p*4+dn)*512 + quad*128 + cd*8 + j
//            (d=dn*16+cd; key=b*64+p*32+(j>=4)*16+quad*4+(j&3))
//   kcF:     idx = (nh*2+half)*512 + quad*128 + cf*8 + j        (cent=nh*16+cf)
//   vtF:     idx = nb*512 + quad*128 + cf*8 + j                 (d=nb*16+cf, c=quad*8+j)
// ============================================================================

// ---- decompose weights + x into bf16 hi/lo planes; seg 6 zeroes d_out -------
__global__ __launch_bounds__(256) void split_w7(
    const float* __restrict__ s0, const float* __restrict__ s1,
    const float* __restrict__ s2, const float* __restrict__ s3,
    const float* __restrict__ s4, const float* __restrict__ s5,
    ush* h0, ush* l0, ush* h1, ush* l1, ush* h2, ush* l2,
    ush* h3, ush* l3, ush* h4, ush* l4, ush* h5, ush* l5,
    float* __restrict__ zout)
{
  int seg = blockIdx.y;
  if (seg == 6) {
    int i = blockIdx.x * 256 + threadIdx.x;
    if (i < (T_TOK*DM)/4) ((float4*)zout)[i] = make_float4(0.f,0.f,0.f,0.f);
    return;
  }
  const float* srcs[6] = {s0, s1, s2, s3, s4, s5};
  ush* hs[6] = {h0, h1, h2, h3, h4, h5};
  ush* ls[6] = {l0, l1, l2, l3, l4, l5};
  const int ns[6] = {1048576, 65536, 65536, 49152, 1048576, 2097152};
  int i = (blockIdx.x * 256 + threadIdx.x) * 4;
  if (i >= ns[seg]) return;
  float4 v = *(const float4*)(srcs[seg] + i);
  ushort4 hv, lv;
  hv.x = f2bf(v.x); lv.x = f2bf(v.x - bf2f(hv.x));
  hv.y = f2bf(v.y); lv.y = f2bf(v.y - bf2f(hv.y));
  hv.z = f2bf(v.z); lv.z = f2bf(v.z - bf2f(hv.z));
  hv.w = f2bf(v.w); lv.w = f2bf(v.w - bf2f(hv.w));
  *(ushort4*)(hs[seg] + i) = hv;
  *(ushort4*)(ls[seg] + i) = lv;
}

// ---- split-bf16 MFMA GEMM body: Y = A @ W^T, 64x64 tile ---------------------
// ymode: 0 = no bf16 out / linear, 1 = Q-fragment, 2 = K-fragment, 3 = V-frag
__device__ __forceinline__ void gemm64_body(
    const float* __restrict__ Af,
    const ush* __restrict__ Ah_, const ush* __restrict__ Al_,
    const ush* __restrict__ Wh, const ush* __restrict__ Wl,
    float* Yf, ush* Yh, ush* Yl, int ymode, int useAtomic,
    ush* Ch, ush* Cl, int ctrans, int cidx, float (*cent)[64],
    int N, int K, int kStart, int kEnd, int m0, int n0,
    ush Ash[64][40], ush Asl[64][40], ush Bsh[64][40], ush Bsl[64][40])
{
  const int tid = threadIdx.x;
  const int wave = tid >> 6, lane = tid & 63;
  const int quad = lane >> 4, c16 = lane & 15;
  const int wm = wave >> 1, wn = wave & 1;
  const int ar = tid >> 2, ac = (tid & 3) * 8;
  f32x4 acc[2][2] = {};
  for (int k0 = kStart; k0 < kEnd; k0 += 32) {
    __syncthreads();
    if (Af) {
      const float* src = Af + (size_t)(m0 + ar) * K + k0 + ac;
      float4 u = *(const float4*)(src);
      float4 w2 = *(const float4*)(src + 4);
      float f[8] = {u.x, u.y, u.z, u.w, w2.x, w2.y, w2.z, w2.w};
      bf16x8 hv, lv;
      #pragma unroll
      for (int j = 0; j < 8; ++j) {
        ush hb = f2bf(f[j]);
        hv[j] = (short)hb;
        lv[j] = (short)f2bf(f[j] - bf2f(hb));
      }
      *(bf16x8*)&Ash[ar][ac] = hv;
      *(bf16x8*)&Asl[ar][ac] = lv;
    } else {
      *(bf16x8*)&Ash[ar][ac] = *(const bf16x8*)(Ah_ + (size_t)(m0 + ar) * K + k0 + ac);
      *(bf16x8*)&Asl[ar][ac] = *(const bf16x8*)(Al_ + (size_t)(m0 + ar) * K + k0 + ac);
    }
    {
      bf16x8 bh = {}, bl = {};
      if (n0 + ar < N) {
        bh = *(const bf16x8*)(Wh + (size_t)(n0 + ar) * K + k0 + ac);
        bl = *(const bf16x8*)(Wl + (size_t)(n0 + ar) * K + k0 + ac);
      }
      *(bf16x8*)&Bsh[ar][ac] = bh;
      *(bf16x8*)&Bsl[ar][ac] = bl;
    }
    __syncthreads();
    bf16x8 Ah[2], Al[2], Bh[2], Bl[2];
    #pragma unroll
    for (int mt = 0; mt < 2; ++mt) {
      Ah[mt] = *(const bf16x8*)&Ash[wm*32 + mt*16 + c16][quad*8];
      Al[mt] = *(const bf16x8*)&Asl[wm*32 + mt*16 + c16][quad*8];
    }
    #pragma unroll
    for (int nt = 0; nt < 2; ++nt) {
      Bh[nt] = *(const bf16x8*)&Bsh[wn*32 + nt*16 + c16][quad*8];
      Bl[nt] = *(const bf16x8*)&Bsl[wn*32 + nt*16 + c16][quad*8];
    }
    #pragma unroll
    for (int mt = 0; mt < 2; ++mt)
      #pragma unroll
      for (int nt = 0; nt < 2; ++nt) {
        acc[mt][nt] = __builtin_amdgcn_mfma_f32_16x16x32_bf16(Ah[mt], Bh[nt], acc[mt][nt], 0, 0, 0);
        acc[mt][nt] = __builtin_amdgcn_mfma_f32_16x16x32_bf16(Ah[mt], Bl[nt], acc[mt][nt], 0, 0, 0);
        acc[mt][nt] = __builtin_amdgcn_mfma_f32_16x16x32_bf16(Al[mt], Bh[nt], acc[mt][nt], 0, 0, 0);
      }
  }
  #pragma unroll
  for (int mt = 0; mt < 2; ++mt)
    #pragma unroll
    for (int nt = 0; nt < 2; ++nt) {
      int n = n0 + wn*32 + nt*16 + c16;
      if (n < N) {
        #pragma unroll
        for (int r = 0; r < 4; ++r) {
          int m = m0 + wm*32 + mt*16 + quad*4 + r;
          float vvv = acc[mt][nt][r];
          if (Yf) {
            if (useAtomic) atomicAdd(&Yf[(size_t)m*N + n], vvv);
            else Yf[(size_t)m*N + n] = vvv;
          }
          if (Yh) {
            ush hb = f2bf(vvv);
            size_t idx;
            if (ymode == 1) {              // Q-frag: t=m, h=n>>6, d=n&63
              int d = n & 63;
              idx = (size_t)m*1024 + (size_t)(d>>5)*512 + (size_t)((d>>3)&3)*128
                  + (size_t)(n>>6)*8 + (d&7);
            } else if (ymode == 2) {       // K-frag: key=m, d=n
              int b = m >> 6, kk = m & 63;
              idx = (size_t)b*4096 + (size_t)(kk>>4)*1024 + (size_t)(n>>5)*512
                  + (size_t)((n>>3)&3)*128 + (size_t)(kk&15)*8 + (n&7);
            } else if (ymode == 3) {       // V-frag: key=m, d=n
              int b = m >> 6, kk = m & 63, rem = kk & 31;
              idx = (size_t)b*4096 + (size_t)((kk>>5)*4 + (n>>4))*512
                  + (size_t)((rem>>2)&3)*128 + (size_t)(n&15)*8
                  + (rem&3) + ((rem>>4)&1)*4;
            } else {
              idx = (size_t)m*N + n;
            }
            Yh[idx] = hb;
            if (Yl) Yl[idx] = f2bf(vvv - bf2f(hb));
          }
        }
      }
    }
  if (Ch) {
    float ps[2];
    #pragma unroll
    for (int nt = 0; nt < 2; ++nt) {
      ps[nt] = 0.f;
      #pragma unroll
      for (int mt = 0; mt < 2; ++mt)
        #pragma unroll
        for (int r = 0; r < 4; ++r) ps[nt] += acc[mt][nt][r];
      ps[nt] += __shfl_xor(ps[nt], 16);
      ps[nt] += __shfl_xor(ps[nt], 32);
      if (quad == 0) cent[wm][wn*32 + nt*16 + c16] = ps[nt];
    }
    __syncthreads();
    if (wm == 0 && quad == 0) {
      #pragma unroll
      for (int nt = 0; nt < 2; ++nt) {
        int n = wn*32 + nt*16 + c16;
        float mval = (cent[0][n] + cent[1][n]) * (1.f/64.f);
        ush hb = f2bf(mval);
        ush lb = f2bf(mval - bf2f(hb));
        size_t idx;
        if (!ctrans) {   // K-centroid fragment: cent=cidx, d=n
          idx = (size_t)((cidx>>4)*2 + (n>>5))*512 + (size_t)((n>>3)&3)*128
              + (size_t)(cidx&15)*8 + (n&7);
        } else {         // V-centroid fragment: d=n, c=cidx
          idx = (size_t)(n>>4)*512 + (size_t)(cidx>>3)*128
              + (size_t)(n&15)*8 + (cidx&7);
        }
        Ch[idx] = hb; Cl[idx] = lb;
      }
    }
  }
}

// fused q + k/v/g projections (+ centroid pooling) in one dispatch
__global__ __launch_bounds__(256) void gemm_proj(
    const ush* __restrict__ xh, const ush* __restrict__ xl,
    const ush* __restrict__ Wqh, const ush* __restrict__ Wql,
    const ush* __restrict__ Wkh, const ush* __restrict__ Wkl,
    const ush* __restrict__ Wvh, const ush* __restrict__ Wvl,
    const ush* __restrict__ Wgh, const ush* __restrict__ Wgl,
    ush* qbF, ush* qlF, ush* kbF, ush* vbF, float* gpj,
    ush* kcF, ush* kcFl, ush* vtF, ush* vtFl, int K)
{
  __shared__ ush Ash[64][40], Asl[64][40], Bsh[64][40], Bsl[64][40];
  __shared__ float cent[2][64];
  const int bx = blockIdx.x;
  if (bx < 16) {
    gemm64_body(nullptr, xh, xl, Wqh, Wql, nullptr, qbF, qlF, 1, 0,
                nullptr, nullptr, 0, 0, nullptr,
                DM, K, 0, K, blockIdx.y*64, bx*64, Ash, Asl, Bsh, Bsl);
  } else if (bx == 16) {
    gemm64_body(nullptr, xh, xl, Wkh, Wkl, nullptr, kbF, nullptr, 2, 0,
                kcF, kcFl, 0, blockIdx.y, cent,
                HD, K, 0, K, blockIdx.y*64, 0, Ash, Asl, Bsh, Bsl);
  } else if (bx == 17) {
    gemm64_body(nullptr, xh, xl, Wvh, Wvl, nullptr, vbF, nullptr, 3, 0,
                vtF, vtFl, 1, blockIdx.y, cent,
                HD, K, 0, K, blockIdx.y*64, 0, Ash, Asl, Bsh, Bsl);
  } else {
    gemm64_body(nullptr, xh, xl, Wgh, Wgl, gpj, nullptr, nullptr, 0, 0,
                nullptr, nullptr, 0, 0, nullptr,
                48, K, 0, K, blockIdx.y*64, 0, Ash, Asl, Bsh, Bsl);
  }
}

// out-projection: A = f32 o inline split; SPLIT-K=2 via f32 atomics
__global__ __launch_bounds__(256) void gemm_out_sk(
    const float* __restrict__ Af,
    const ush* __restrict__ Wh, const ush* __restrict__ Wl,
    float* Yf, int N, int K)
{
  __shared__ ush Ash[64][40], Asl[64][40], Bsh[64][40], Bsl[64][40];
  const int kHalf = K >> 1;
  const int kStart = blockIdx.z * kHalf;
  gemm64_body(Af, nullptr, nullptr, Wh, Wl, Yf, nullptr, nullptr, 0, 1,
              nullptr, nullptr, 0, 0, nullptr,
              N, K, kStart, kStart + kHalf, blockIdx.y*64, blockIdx.x*64,
              Ash, Asl, Bsh, Bsl);
}

// ---- compressed attention + top-k; all loads now fragment-order coalesced ---
__global__ __launch_bounds__(256) void cmp_attn_mfma(
    const ush* __restrict__ qbF, const ush* __restrict__ qlF,
    const ush* __restrict__ kcF, const ush* __restrict__ kcFl,
    const ush* __restrict__ vtF, const ush* __restrict__ vtFl,
    float* __restrict__ ocmp, int* __restrict__ blkp)
{
  __shared__ float Pls[4][16][36];
  const int tid = threadIdx.x, w = tid >> 6, lane = tid & 63;
  const int quad = lane >> 4, c16 = lane & 15;
  const int t = blockIdx.x * 4 + w;

  const ush* qt = qbF + (size_t)t*DM + lane*8;
  const ush* ql = qlF + (size_t)t*DM + lane*8;
  bf16x8 qah0 = *(const bf16x8*)(qt);
  bf16x8 qah1 = *(const bf16x8*)(qt + 512);
  bf16x8 qal0 = *(const bf16x8*)(ql);
  bf16x8 qal1 = *(const bf16x8*)(ql + 512);

  f32x4 s[2];
  #pragma unroll
  for (int nh = 0; nh < 2; ++nh) {
    bf16x8 kh0 = *(const bf16x8*)(kcF  + (nh*2+0)*512 + lane*8);
    bf16x8 kh1 = *(const bf16x8*)(kcF  + (nh*2+1)*512 + lane*8);
    bf16x8 kl0 = *(const bf16x8*)(kcFl + (nh*2+0)*512 + lane*8);
    bf16x8 kl1 = *(const bf16x8*)(kcFl + (nh*2+1)*512 + lane*8);
    f32x4 acc = {0.f, 0.f, 0.f, 0.f};
    acc = __builtin_amdgcn_mfma_f32_16x16x32_bf16(qah0, kh0, acc, 0, 0, 0);
    acc = __builtin_amdgcn_mfma_f32_16x16x32_bf16(qah1, kh1, acc, 0, 0, 0);
    acc = __builtin_amdgcn_mfma_f32_16x16x32_bf16(qah0, kl0, acc, 0, 0, 0);
    acc = __builtin_amdgcn_mfma_f32_16x16x32_bf16(qah1, kl1, acc, 0, 0, 0);
    acc = __builtin_amdgcn_mfma_f32_16x16x32_bf16(qal0, kh0, acc, 0, 0, 0);
    acc = __builtin_amdgcn_mfma_f32_16x16x32_bf16(qal1, kh1, acc, 0, 0, 0);
    s[nh] = acc;
  }

  const int nvis = (t + 1) >> 6;
  const bool visA = (c16 < nvis), visB = (16 + c16 < nvis);
  float p[2][4];
  float iA = 0.f, iB = 0.f;
  #pragma unroll
  for (int r = 0; r < 4; ++r) {
    float sA = s[0][r] * 0.125f, sB = s[1][r] * 0.125f;
    float m = fmaxf(visA ? sA : -INFINITY, visB ? sB : -INFINITY);
    #pragma unroll
    for (int off = 1; off < 16; off <<= 1) m = fmaxf(m, __shfl_xor(m, off));
    float eA = visA ? __expf(sA - m) : 0.f;
    float eB = visB ? __expf(sB - m) : 0.f;
    float l = eA + eB;
    #pragma unroll
    for (int off = 1; off < 16; off <<= 1) l += __shfl_xor(l, off);
    float inv = (l > 0.f) ? 1.f / l : 0.f;
    p[0][r] = eA * inv; p[1][r] = eB * inv;
    iA += p[0][r]; iB += p[1][r];
  }
  iA += __shfl_xor(iA, 16); iA += __shfl_xor(iA, 32);
  iB += __shfl_xor(iB, 16); iB += __shfl_xor(iB, 32);

  #pragma unroll
  for (int nh = 0; nh < 2; ++nh)
    #pragma unroll
    for (int r = 0; r < 4; ++r)
      Pls[w][quad*4 + r][nh*16 + c16] = p[nh][r];

  {
    const int cur = t >> 6;
    float a;
    if (lane < 16) a = iA;
    else if (lane < 32) a = iB;
    else a = -INFINITY;
    if (lane < 32) {
      if (lane > cur) a = NEGF;
      if (lane == 0 || lane == cur) a = INFINITY;
    }
    for (int sidx = 0; sidx < S_SEL; ++sidx) {
      float bv = a; int bi = lane;
      #pragma unroll
      for (int off = 1; off < 64; off <<= 1) {
        float ov = __shfl_xor(bv, off); int oi = __shfl_xor(bi, off);
        if (ov > bv || (ov == bv && oi < bi)) { bv = ov; bi = oi; }
      }
      if (lane == 0) blkp[t*S_SEL + sidx] = bi;
      if (lane == bi) a = -INFINITY;
    }
  }
  __syncthreads();

  float4 pa = *(const float4*)&Pls[w][c16][quad*8];
  float4 pb = *(const float4*)&Pls[w][c16][quad*8 + 4];
  float pf[8] = {pa.x, pa.y, pa.z, pa.w, pb.x, pb.y, pb.z, pb.w};
  bf16x8 pah, pal;
  #pragma unroll
  for (int j = 0; j < 8; ++j) {
    ush hb = f2bf(pf[j]);
    pah[j] = (short)hb;
    pal[j] = (short)f2bf(pf[j] - bf2f(hb));
  }
  #pragma unroll
  for (int nb = 0; nb < 4; ++nb) {
    bf16x8 vh8 = *(const bf16x8*)(vtF  + nb*512 + lane*8);
    bf16x8 vl8 = *(const bf16x8*)(vtFl + nb*512 + lane*8);
    f32x4 acc = {0.f, 0.f, 0.f, 0.f};
    acc = __builtin_amdgcn_mfma_f32_16x16x32_bf16(pah, vh8, acc, 0, 0, 0);
    acc = __builtin_amdgcn_mfma_f32_16x16x32_bf16(pah, vl8, acc, 0, 0, 0);
    acc = __builtin_amdgcn_mfma_f32_16x16x32_bf16(pal, vh8, acc, 0, 0, 0);
    #pragma unroll
    for (int r = 0; r < 4; ++r)
      ocmp[(size_t)t*DM + (quad*4 + r)*HD + nb*16 + c16] = acc[r];
  }
}

// ---- selected attention: swapped-operand, FRAGMENT-ORDER coalesced loads ----
// R2 structure (zero loop-LDS, validated) with kbF/vbF/qbF addressing: every
// load in the chain is base + lane*16B -> 16 line-requests instead of ~64
// scattered transactions. Per-chain memory cost drops ~4x, which R0-R4's
// counter history identified as the conserved limiter.
__global__ __launch_bounds__(256) void sel_attn_frag(
    const ush* __restrict__ qbF, const ush* __restrict__ kbF,
    const ush* __restrict__ vbF, const float* __restrict__ gp,
    const int* __restrict__ blkp, float* __restrict__ ocmp_io)
{
  __shared__ float cO2[4][4][16][17];
  __shared__ float cL[4][16];

  const int tid = threadIdx.x, w = tid >> 6, lane = tid & 63;
  const int quad = lane >> 4, c16 = lane & 15;
  const int t = T_TOK - 1 - blockIdx.x;         // heavy tokens first
  const int cur = t >> 6;
  const int nblk = (cur + 1 < S_SEL) ? cur + 1 : S_SEL;

  int myblk = 0;
  if (lane < S_SEL) myblk = blkp[t*S_SEL + lane];
  const int nb_w = (nblk > w) ? (((nblk - 1 - w) >> 2) + 1) : 0;

  // Q fragment (head = c16, d = quad*8+j / +32) — coalesced
  const ush* qt = qbF + (size_t)t*DM + lane*8;
  bf16x8 qa0 = *(const bf16x8*)(qt);
  bf16x8 qa1 = *(const bf16x8*)(qt + 512);

  f32x4 accO[4] = {};                           // O^T[d=dn*16+quad*4+r][h=c16]
  float lacc = 0.f;                             // denom partial for head c16

  for (int i = 0; i < nb_w; ++i) {
    const int blk = __shfl(myblk, w + (i << 2));
    const int bs = blk * BS;
    const ush* kB = kbF + (size_t)blk * 4096 + lane*8;
    const ush* vB = vbF + (size_t)blk * 4096 + lane*8;

    // K fragments — 8 coalesced 16B/lane loads
    bf16x8 kf0[4], kf1[4];
    #pragma unroll
    for (int nc = 0; nc < 4; ++nc) {
      kf0[nc] = *(const bf16x8*)(kB + nc*1024);
      kf1[nc] = *(const bf16x8*)(kB + nc*1024 + 512);
    }
    // V fragments — 8 coalesced 16B/lane loads (latency hides under QK/exp)
    bf16x8 vf[4][2];
    #pragma unroll
    for (int p = 0; p < 2; ++p)
      #pragma unroll
      for (int dn = 0; dn < 4; ++dn)
        vf[dn][p] = *(const bf16x8*)(vB + (p*4 + dn)*512);

    // S^T = K Q^T  (lane: head = c16, key = bs + nc*16 + quad*4 + r)
    f32x4 sc[4];
    #pragma unroll
    for (int nc = 0; nc < 4; ++nc) {
      f32x4 a = {0.f, 0.f, 0.f, 0.f};
      a = __builtin_amdgcn_mfma_f32_16x16x32_bf16(kf0[nc], qa0, a, 0, 0, 0);
      a = __builtin_amdgcn_mfma_f32_16x16x32_bf16(kf1[nc], qa1, a, 0, 0, 0);
      sc[nc] = a;
    }

    // mask + exp + pack: P^T stays in registers as two B-fragments
    ush pf[16];
    #pragma unroll
    for (int nc = 0; nc < 4; ++nc) {
      const int k0 = bs + nc*16 + quad*4;
      #pragma unroll
      for (int r = 0; r < 4; ++r) {
        float e = (k0 + r <= t) ? __expf(sc[nc][r] * 0.125f) : 0.f;
        lacc += e;
        pf[nc*4 + r] = f2bf(e);
      }
    }
    bf16x8 P01, P23;
    #pragma unroll
    for (int j = 0; j < 8; ++j) {
      P01[j] = (short)pf[j];
      P23[j] = (short)pf[8 + j];
    }

    // O^T += V^T P^T (two 16-key chunks per MFMA)
    #pragma unroll
    for (int dn = 0; dn < 4; ++dn) {
      accO[dn] = __builtin_amdgcn_mfma_f32_16x16x32_bf16(vf[dn][0], P01, accO[dn], 0, 0, 0);
      accO[dn] = __builtin_amdgcn_mfma_f32_16x16x32_bf16(vf[dn][1], P23, accO[dn], 0, 0, 0);
    }
  }

  // wave-local denominator: sum over quads -> every lane has the full sum
  lacc += __shfl_xor(lacc, 16);
  lacc += __shfl_xor(lacc, 32);

  // ---- cross-wave combine ----
  if (quad == 0) cL[w][c16] = lacc;
  #pragma unroll
  for (int dn = 0; dn < 4; ++dn)
    #pragma unroll
    for (int r = 0; r < 4; ++r)
      cO2[w][dn][quad*4 + r][c16] = accO[dn][r];
  __syncthreads();

  // output (h = i*4+w uniform per wave; d = lane -> fully coalesced I/O)
  #pragma unroll
  for (int i = 0; i < 4; ++i) {
    const int h = i*4 + w;
    float L = cL[0][h] + cL[1][h] + cL[2][h] + cL[3][h];
    float O = cO2[0][quad][c16][h] + cO2[1][quad][c16][h]
            + cO2[2][quad][c16][h] + cO2[3][quad][c16][h];
    float ga = gp[(size_t)t*48 + h*3 + 0];
    float gb = gp[(size_t)t*48 + h*3 + 1];
    float gcv = 1.f/(1.f + __expf(-ga));
    float gsv = 1.f/(1.f + __expf(-gb));
    size_t idx = (size_t)t*DM + (size_t)h*HD + lane;
    ocmp_io[idx] = O * gsv / L + ocmp_io[idx] * gcv;
  }
}

extern "C" void kernel_launch(void* const* d_in, const int* in_sizes, int n_in,
                              void* d_out, int out_size, void* d_ws, size_t ws_size,
                              hipStream_t stream)
{
  const float* x  = (const float*)d_in[0];
  const float* Wq = (const float*)d_in[1];
  const float* Wk = (const float*)d_in[2];
  const float* Wv = (const float*)d_in[3];
  const float* Wg = (const float*)d_in[4];
  const float* Wo = (const float*)d_in[5];
  float* out = (float*)d_out;

  float* ws   = (float*)d_ws;
  float* gpj  = ws;                                // 2048*48 f32
  float* ocmp = gpj + (size_t)T_TOK*48;            // 2048*1024 f32 (combined o)
  ush* xh  = (ush*)(ocmp + (size_t)T_TOK*DM);      // 2048*1024
  ush* xl  = xh + (size_t)T_TOK*DM;
  ush* qbF = xl + (size_t)T_TOK*DM;                // Q fragment-order
  ush* qlF = qbF + (size_t)T_TOK*DM;
  ush* kbF = qlF + (size_t)T_TOK*DM;               // K fragment-order (2048*64)
  ush* vbF = kbF + (size_t)T_TOK*HD;               // V fragment-order (2048*64)
  ush* kcF = vbF + (size_t)T_TOK*HD;
  ush* kcFl = kcF + NB*HD;
  ush* vtF = kcFl + NB*HD;
  ush* vtFl = vtF + NB*HD;
  ush* Wqh = vtFl + NB*HD;
  ush* Wql = Wqh + 1048576;
  ush* Wkh = Wql + 1048576;
  ush* Wkl = Wkh + 65536;
  ush* Wvh = Wkl + 65536;
  ush* Wvl = Wvh + 65536;
  ush* Wgh = Wvl + 65536;
  ush* Wgl = Wgh + 49152;
  ush* Woh = Wgl + 49152;
  ush* Wol = Woh + 1048576;
  int* blkp = (int*)(Wol + 1048576);               // 2048*16

  split_w7<<<dim3(2048, 7), 256, 0, stream>>>(Wq, Wk, Wv, Wg, Wo, x,
      Wqh, Wql, Wkh, Wkl, Wvh, Wvl, Wgh, Wgl, Woh, Wol, xh, xl, out);
  gemm_proj<<<dim3(19, 32), 256, 0, stream>>>(xh, xl, Wqh, Wql,
      Wkh, Wkl, Wvh, Wvl, Wgh, Wgl, qbF, qlF, kbF, vbF, gpj,
      kcF, kcFl, vtF, vtFl, DM);
  cmp_attn_mfma<<<T_TOK/4, 256, 0, stream>>>(qbF, qlF, kcF, kcFl, vtF, vtFl,
      ocmp, blkp);
  sel_attn_frag<<<T_TOK, 256, 0, stream>>>(qbF, kbF, vbF, gpj, blkp, ocmp);
  gemm_out_sk<<<dim3(16, 32, 2), 256, 0, stream>>>(ocmp, Woh, Wol, out, DM, DM);
}